// Round 3
// baseline (61710.052 us; speedup 1.0000x reference)
//
#include <hip/hip_runtime.h>
#include <hip/hip_bf16.h>

#define N_LAYER 4
#define N_HEAD 16
#define D_MODEL 1024
#define D_HEAD 64
#define D_INNER 4096
#define TGT_LEN 512
#define MEM_LEN 512
#define KLEN (TGT_LEN + MEM_LEN)   // 1024
#define BSZ 8

typedef unsigned short ushort;

__device__ __forceinline__ float bf2f(ushort u) {
    union { unsigned int i; float f; } x; x.i = ((unsigned int)u) << 16; return x.f;
}
__device__ __forceinline__ ushort f2bf(float f) {
    unsigned int x = __float_as_uint(f);
    unsigned int r = (x + 0x7fffu + ((x >> 16) & 1u)) >> 16;
    return (ushort)r;
}
// dtype-flexible scalar load: flag!=0 -> fp32 data, flag==0 -> bf16 data
__device__ __forceinline__ float ldin(const void* p, size_t i, int fp32) {
    return fp32 ? ((const float*)p)[i] : bf2f(((const ushort*)p)[i]);
}

// ---------------------------------------------------------------------------
// Detect input float dtype by sampling emb_table. Writes 1 (fp32) or 0 (bf16).
__global__ __launch_bounds__(256) void detect_kernel(
    const ushort* __restrict__ emb_u, int* __restrict__ flag)
{
    __shared__ int cnt[256];
    int c = 0;
    for (int k = threadIdx.x; k < 4096; k += 256) {
        ushort u = emb_u[2 * k];
        int e = (u >> 7) & 0xFF;
        if (u == 0 || (e >= 96 && e <= 130)) c++;
    }
    cnt[threadIdx.x] = c; __syncthreads();
    for (int w = 128; w > 0; w >>= 1) {
        if (threadIdx.x < w) cnt[threadIdx.x] += cnt[threadIdx.x + w];
        __syncthreads();
    }
    if (threadIdx.x == 0) *flag = (cnt[0] < 2048) ? 1 : 0;
}

// ---------------------------------------------------------------------------
__global__ __launch_bounds__(256) void embed_kernel(
    const int* __restrict__ inp, const void* __restrict__ emb,
    float* __restrict__ core, const int* __restrict__ flag)
{
    const int fp32 = *flag;
    const int row = blockIdx.x;
    const int t = threadIdx.x;
    const int tok = inp[row];
    float* c = core + (size_t)row * D_MODEL;
#pragma unroll
    for (int cidx = 0; cidx < 4; ++cidx) {
        int d = t + 256 * cidx;
        c[d] = ldin(emb, (size_t)tok * D_MODEL + d, fp32) * 32.0f;
    }
}

// ---------------------------------------------------------------------------
__global__ __launch_bounds__(256) void pos_kernel(float* __restrict__ pos)
{
    const int j = blockIdx.x;
    const int t = threadIdx.x;
    const float p = (float)(KLEN - 1 - j);
    const float lg = logf(10000.0f);
    float* row = pos + (size_t)j * D_MODEL;
#pragma unroll
    for (int cidx = 0; cidx < 4; ++cidx) {
        int d = t + 256 * cidx;
        int f = (d < 512) ? d : (d - 512);
        float invf = expf(-((float)(2 * f) / (float)D_MODEL) * lg);
        float a = p * invf;
        row[d] = (d < 512) ? sinf(a) : cosf(a);
    }
}

// ---------------------------------------------------------------------------
__global__ __launch_bounds__(256) void concat_kernel(
    const void* __restrict__ mems, size_t moff, const float* __restrict__ core,
    float* __restrict__ cat, const int* __restrict__ flag)
{
    const int fp32 = *flag;
    const int r = blockIdx.x;
    const int t = threadIdx.x;
    float* dst = cat + (size_t)r * D_MODEL;
    if (r < MEM_LEN * BSZ) {
#pragma unroll
        for (int cidx = 0; cidx < 4; ++cidx) {
            int d = t + 256 * cidx;
            dst[d] = ldin(mems, moff + (size_t)r * D_MODEL + d, fp32);
        }
    } else {
        const float* src = core + (size_t)(r - MEM_LEN * BSZ) * D_MODEL;
#pragma unroll
        for (int cidx = 0; cidx < 4; ++cidx) {
            int d = t + 256 * cidx;
            dst[d] = src[d];
        }
    }
}

// ---------------------------------------------------------------------------
// C[M,N] = A[M,K] * W[N,K]^T (+bias, +relu). A fp32, W dtype per flag, C fp32.
template<bool BIAS, bool RELU>
__global__ __launch_bounds__(256) void gemm_awt(
    const float* __restrict__ A, const void* __restrict__ W, size_t woff,
    const void* __restrict__ bias, size_t boff, float* __restrict__ C,
    int M, int N, int K, const int* __restrict__ flag)
{
    const int fp32 = *flag;
    __shared__ float As[16][65];
    __shared__ float Ws[16][65];
    const int m0 = blockIdx.y * 64;
    const int n0 = blockIdx.x * 64;
    const int t = threadIdx.x;
    const int lr = t >> 2;
    const int lc = (t & 3) << 2;
    const int tn = t & 15;
    const int tm = t >> 4;
    float acc[4][4] = {};

    for (int k0 = 0; k0 < K; k0 += 16) {
        const float4 av = *reinterpret_cast<const float4*>(
            &A[(size_t)(m0 + lr) * K + k0 + lc]);
        As[lc + 0][lr] = av.x; As[lc + 1][lr] = av.y;
        As[lc + 2][lr] = av.z; As[lc + 3][lr] = av.w;
        const size_t widx = woff + (size_t)(n0 + lr) * K + k0 + lc;
        float w0, w1, w2, w3;
        if (fp32) {
            const float4 wv = *reinterpret_cast<const float4*>((const float*)W + widx);
            w0 = wv.x; w1 = wv.y; w2 = wv.z; w3 = wv.w;
        } else {
            const ushort4 wv = *reinterpret_cast<const ushort4*>((const ushort*)W + widx);
            w0 = bf2f(wv.x); w1 = bf2f(wv.y); w2 = bf2f(wv.z); w3 = bf2f(wv.w);
        }
        Ws[lc + 0][lr] = w0; Ws[lc + 1][lr] = w1;
        Ws[lc + 2][lr] = w2; Ws[lc + 3][lr] = w3;
        __syncthreads();
#pragma unroll
        for (int kk = 0; kk < 16; ++kk) {
            float a[4], w[4];
#pragma unroll
            for (int i = 0; i < 4; ++i) a[i] = As[kk][tm * 4 + i];
#pragma unroll
            for (int j = 0; j < 4; ++j) w[j] = Ws[kk][tn * 4 + j];
#pragma unroll
            for (int i = 0; i < 4; ++i)
#pragma unroll
                for (int j = 0; j < 4; ++j)
                    acc[i][j] += a[i] * w[j];
        }
        __syncthreads();
    }

#pragma unroll
    for (int i = 0; i < 4; ++i) {
        const int m = m0 + tm * 4 + i;
#pragma unroll
        for (int j = 0; j < 4; ++j) {
            const int n = n0 + tn * 4 + j;
            float v = acc[i][j];
            if (BIAS) v += ldin(bias, boff + n, fp32);
            if (RELU) v = fmaxf(v, 0.0f);
            C[(size_t)m * N + n] = v;
        }
    }
}

// ---------------------------------------------------------------------------
// Flash-style relative attention.
// Block = (i-tile of 64, b, n). 256 threads, 64x64x64 register-tiled phases:
//   E-panel GEMMs (BD term), AC GEMM, online softmax, PV GEMM.
// S[i,j] = 0.125*(qw_i.k_j + qr_i.rk[j+511-i]), mask j > i+512.
__global__ __launch_bounds__(256, 3) void attn_flash_kernel(
    const float* __restrict__ q, const float* __restrict__ k,
    const float* __restrict__ v, const float* __restrict__ rk,
    const void* __restrict__ rwb, const void* __restrict__ rrb,
    float* __restrict__ vec, const int* __restrict__ flag)
{
    const int fp32 = *flag;
    const int it = blockIdx.x;          // i-tile index, i0 = 64*it
    const int b  = blockIdx.y;
    const int n  = blockIdx.z;
    const int t  = threadIdx.x;
    const int i0 = it * 64;

    __shared__ __align__(16) ushort qwT[64][68];   // [d][il], bf16
    __shared__ __align__(16) ushort qrT[64][68];   // [d][il], bf16
    __shared__ __align__(16) float  stageF[64 * 68]; // ksT/rkT [d][col] or Vs [j][d]
    __shared__ __align__(16) ushort ebuf[2][64][66]; // E panels [panel][il][cl], bf16
    float* psf = reinterpret_cast<float*>(&ebuf[0][0][0]); // P tile alias [64][65]

    const int tm = t >> 4, tn = t & 15;
    const int tm4 = tm * 4, tn4 = tn * 4;

    // ---- prologue: stage qw/qr tiles (transposed, bf16) ----
#pragma unroll
    for (int r = 0; r < 4; ++r) {
        const int idx = t + 256 * r;
        const int il = idx >> 4;
        const int d4 = (idx & 15) * 4;
        const float4 qv = *reinterpret_cast<const float4*>(
            &q[((size_t)(i0 + il) * BSZ + b) * D_MODEL + n * 64 + d4]);
        const float bw0 = ldin(rwb, n * 64 + d4 + 0, fp32);
        const float bw1 = ldin(rwb, n * 64 + d4 + 1, fp32);
        const float bw2 = ldin(rwb, n * 64 + d4 + 2, fp32);
        const float bw3 = ldin(rwb, n * 64 + d4 + 3, fp32);
        const float br0 = ldin(rrb, n * 64 + d4 + 0, fp32);
        const float br1 = ldin(rrb, n * 64 + d4 + 1, fp32);
        const float br2 = ldin(rrb, n * 64 + d4 + 2, fp32);
        const float br3 = ldin(rrb, n * 64 + d4 + 3, fp32);
        qwT[d4 + 0][il] = f2bf(qv.x + bw0);
        qwT[d4 + 1][il] = f2bf(qv.y + bw1);
        qwT[d4 + 2][il] = f2bf(qv.z + bw2);
        qwT[d4 + 3][il] = f2bf(qv.w + bw3);
        qrT[d4 + 0][il] = f2bf(qv.x + br0);
        qrT[d4 + 1][il] = f2bf(qv.y + br1);
        qrT[d4 + 2][il] = f2bf(qv.z + br2);
        qrT[d4 + 3][il] = f2bf(qv.w + br3);
    }
    __syncthreads();

    float O[4][4] = {};
    float mrow[4], lrow[4];
#pragma unroll
    for (int ii = 0; ii < 4; ++ii) { mrow[ii] = -1e30f; lrow[ii] = 0.0f; }

    const int ntiles = it + 9;
    for (int jt = 0; jt < ntiles; ++jt) {
        const int j0 = jt * 64;
        const int base = j0 - i0 + 448;     // >= 0; jj = base + c, c = jl-il+63

        // ---- E panels: E[il][c] = qr_il . rk[base+c], c in [0,128) ----
#pragma unroll 1
        for (int panel = 0; panel < 2; ++panel) {
#pragma unroll
            for (int r = 0; r < 4; ++r) {
                const int idx = t + 256 * r;
                const int cl = idx >> 4;
                const int d4 = (idx & 15) * 4;
                const int jj = base + panel * 64 + cl;
                float4 rv = make_float4(0.f, 0.f, 0.f, 0.f);
                if (jj < KLEN)
                    rv = *reinterpret_cast<const float4*>(
                        &rk[(size_t)jj * D_MODEL + n * 64 + d4]);
                stageF[(d4 + 0) * 68 + cl] = rv.x;
                stageF[(d4 + 1) * 68 + cl] = rv.y;
                stageF[(d4 + 2) * 68 + cl] = rv.z;
                stageF[(d4 + 3) * 68 + cl] = rv.w;
            }
            __syncthreads();
            float e[4][4] = {};
#pragma unroll
            for (int d = 0; d < 64; ++d) {
                const ushort4 au = *reinterpret_cast<const ushort4*>(&qrT[d][tm4]);
                const float4 bv = *reinterpret_cast<const float4*>(&stageF[d * 68 + tn4]);
                const float a0 = bf2f(au.x), a1 = bf2f(au.y), a2 = bf2f(au.z), a3 = bf2f(au.w);
                e[0][0] += a0 * bv.x; e[0][1] += a0 * bv.y; e[0][2] += a0 * bv.z; e[0][3] += a0 * bv.w;
                e[1][0] += a1 * bv.x; e[1][1] += a1 * bv.y; e[1][2] += a1 * bv.z; e[1][3] += a1 * bv.w;
                e[2][0] += a2 * bv.x; e[2][1] += a2 * bv.y; e[2][2] += a2 * bv.z; e[2][3] += a2 * bv.w;
                e[3][0] += a3 * bv.x; e[3][1] += a3 * bv.y; e[3][2] += a3 * bv.z; e[3][3] += a3 * bv.w;
            }
            __syncthreads();   // stageF reads done before next overwrite
#pragma unroll
            for (int ii = 0; ii < 4; ++ii)
#pragma unroll
                for (int j2 = 0; j2 < 4; ++j2)
                    ebuf[panel][tm4 + ii][tn4 + j2] = f2bf(e[ii][j2]);
        }

        // ---- stage K tile [d][jl] ----
#pragma unroll
        for (int r = 0; r < 4; ++r) {
            const int idx = t + 256 * r;
            const int jl = idx >> 4;
            const int d4 = (idx & 15) * 4;
            const float4 kv = *reinterpret_cast<const float4*>(
                &k[((size_t)(j0 + jl) * BSZ + b) * D_MODEL + n * 64 + d4]);
            stageF[(d4 + 0) * 68 + jl] = kv.x;
            stageF[(d4 + 1) * 68 + jl] = kv.y;
            stageF[(d4 + 2) * 68 + jl] = kv.z;
            stageF[(d4 + 3) * 68 + jl] = kv.w;
        }
        __syncthreads();       // also publishes ebuf writes

        // ---- AC GEMM ----
        float s[4][4] = {};
#pragma unroll
        for (int d = 0; d < 64; ++d) {
            const ushort4 au = *reinterpret_cast<const ushort4*>(&qwT[d][tm4]);
            const float4 bv = *reinterpret_cast<const float4*>(&stageF[d * 68 + tn4]);
            const float a0 = bf2f(au.x), a1 = bf2f(au.y), a2 = bf2f(au.z), a3 = bf2f(au.w);
            s[0][0] += a0 * bv.x; s[0][1] += a0 * bv.y; s[0][2] += a0 * bv.z; s[0][3] += a0 * bv.w;
            s[1][0] += a1 * bv.x; s[1][1] += a1 * bv.y; s[1][2] += a1 * bv.z; s[1][3] += a1 * bv.w;
            s[2][0] += a2 * bv.x; s[2][1] += a2 * bv.y; s[2][2] += a2 * bv.z; s[2][3] += a2 * bv.w;
            s[3][0] += a3 * bv.x; s[3][1] += a3 * bv.y; s[3][2] += a3 * bv.z; s[3][3] += a3 * bv.w;
        }

        // ---- assemble scores (+E, mask, scale) & per-row max ----
        float rmax[4];
#pragma unroll
        for (int ii = 0; ii < 4; ++ii) {
            const int il = tm4 + ii;
            const int i = i0 + il;
            float rm = -1e30f;
#pragma unroll
            for (int j2 = 0; j2 < 4; ++j2) {
                const int jl = tn4 + j2;
                const int c = jl - il + 63;           // [0,126]
                const float e = bf2f(ebuf[c >> 6][il][c & 63]);
                float sc;
                if (j0 + jl > i + 512) sc = -1e30f;
                else sc = (s[ii][j2] + e) * 0.125f;
                s[ii][j2] = sc;
                rm = fmaxf(rm, sc);
            }
            rmax[ii] = rm;
        }
#pragma unroll
        for (int m = 1; m < 16; m <<= 1)
#pragma unroll
            for (int ii = 0; ii < 4; ++ii)
                rmax[ii] = fmaxf(rmax[ii], __shfl_xor(rmax[ii], m));

        // ---- online softmax update ----
        float p[4][4], alpha[4], rsum[4];
#pragma unroll
        for (int ii = 0; ii < 4; ++ii) {
            const float mnew = fmaxf(mrow[ii], rmax[ii]);
            alpha[ii] = __expf(mrow[ii] - mnew);
            mrow[ii] = mnew;
            float rs = 0.f;
#pragma unroll
            for (int j2 = 0; j2 < 4; ++j2) {
                const float pe = __expf(s[ii][j2] - mnew);
                p[ii][j2] = pe;
                rs += pe;
            }
            rsum[ii] = rs;
        }
#pragma unroll
        for (int m = 1; m < 16; m <<= 1)
#pragma unroll
            for (int ii = 0; ii < 4; ++ii)
                rsum[ii] += __shfl_xor(rsum[ii], m);
#pragma unroll
        for (int ii = 0; ii < 4; ++ii) {
            lrow[ii] = lrow[ii] * alpha[ii] + rsum[ii];
#pragma unroll
            for (int dd = 0; dd < 4; ++dd) O[ii][dd] *= alpha[ii];
        }
        __syncthreads();       // done reading ebuf (E) & stageF (K)

        // ---- write P tile (aliases ebuf) + stage V tile [jl][d] ----
#pragma unroll
        for (int ii = 0; ii < 4; ++ii)
#pragma unroll
            for (int j2 = 0; j2 < 4; ++j2)
                psf[(tm4 + ii) * 65 + tn4 + j2] = p[ii][j2];
#pragma unroll
        for (int r = 0; r < 4; ++r) {
            const int idx = t + 256 * r;
            const int jl = idx >> 4;
            const int d4 = (idx & 15) * 4;
            const float4 vv = *reinterpret_cast<const float4*>(
                &v[((size_t)(j0 + jl) * BSZ + b) * D_MODEL + n * 64 + d4]);
            *reinterpret_cast<float4*>(&stageF[jl * 68 + d4]) = vv;
        }
        __syncthreads();

        // ---- PV GEMM: O[il][d] += sum_jl P[il][jl] * V[jl][d] ----
#pragma unroll
        for (int jl = 0; jl < 64; ++jl) {
            const float4 vv = *reinterpret_cast<const float4*>(&stageF[jl * 68 + tn4]);
            float pr[4];
#pragma unroll
            for (int ii = 0; ii < 4; ++ii) pr[ii] = psf[(tm4 + ii) * 65 + jl];
#pragma unroll
            for (int ii = 0; ii < 4; ++ii) {
                O[ii][0] += pr[ii] * vv.x;
                O[ii][1] += pr[ii] * vv.y;
                O[ii][2] += pr[ii] * vv.z;
                O[ii][3] += pr[ii] * vv.w;
            }
        }
        __syncthreads();       // before next tile overwrites stageF/ebuf
    }

    // ---- epilogue ----
#pragma unroll
    for (int ii = 0; ii < 4; ++ii) {
        const float invl = 1.0f / lrow[ii];
        float4 o4;
        o4.x = O[ii][0] * invl; o4.y = O[ii][1] * invl;
        o4.z = O[ii][2] * invl; o4.w = O[ii][3] * invl;
        *reinterpret_cast<float4*>(
            &vec[((size_t)(i0 + tm4 + ii) * BSZ + b) * D_MODEL + n * 64 + tn4]) = o4;
    }
}

// ---------------------------------------------------------------------------
__global__ __launch_bounds__(256) void add_ln_kernel(
    float* __restrict__ core, const float* __restrict__ resid,
    const void* __restrict__ g, size_t goff,
    const void* __restrict__ bta, size_t boff, const int* __restrict__ flag)
{
    const int fp32 = *flag;
    const int row = blockIdx.x;
    const int t = threadIdx.x;
    __shared__ float sm[256];
    float x[4];
    float sum = 0.f;
    float* c = core + (size_t)row * D_MODEL;
    const float* r = resid + (size_t)row * D_MODEL;
#pragma unroll
    for (int ci = 0; ci < 4; ++ci) {
        int d = t + 256 * ci;
        x[ci] = c[d] + r[d];
        sum += x[ci];
    }
    sm[t] = sum; __syncthreads();
    for (int w = 128; w > 0; w >>= 1) {
        if (t < w) sm[t] += sm[t + w];
        __syncthreads();
    }
    const float mean = sm[0] * (1.0f / D_MODEL);
    __syncthreads();
    float vs = 0.f;
#pragma unroll
    for (int ci = 0; ci < 4; ++ci) {
        float dlt = x[ci] - mean;
        vs += dlt * dlt;
    }
    sm[t] = vs; __syncthreads();
    for (int w = 128; w > 0; w >>= 1) {
        if (t < w) sm[t] += sm[t + w];
        __syncthreads();
    }
    const float rstd = rsqrtf(sm[0] * (1.0f / D_MODEL) + 1e-5f);
    __syncthreads();
#pragma unroll
    for (int ci = 0; ci < 4; ++ci) {
        int d = t + 256 * ci;
        c[d] = (x[ci] - mean) * rstd * ldin(g, goff + d, fp32) + ldin(bta, boff + d, fp32);
    }
}

// ---------------------------------------------------------------------------
__global__ __launch_bounds__(256) void cast_out_kernel(
    const float* __restrict__ core, void* __restrict__ out,
    const int* __restrict__ flag)
{
    const int fp32 = *flag;
    const int idx = blockIdx.x * 256 + threadIdx.x;
    if (fp32) ((float*)out)[idx] = core[idx];
    else      ((ushort*)out)[idx] = f2bf(core[idx]);
}

// ---------------------------------------------------------------------------
extern "C" void kernel_launch(void* const* d_in, const int* in_sizes, int n_in,
                              void* d_out, int out_size, void* d_ws, size_t ws_size,
                              hipStream_t stream)
{
    const int*  inp      = (const int*)d_in[0];
    const void* mems     = d_in[1];
    const void* emb      = d_in[2];
    const void* r_w_bias = d_in[3];
    const void* r_r_bias = d_in[4];
    const void* qkv_w    = d_in[5];
    const void* r_w      = d_in[6];
    const void* o_w      = d_in[7];
    const void* ln1_g    = d_in[8];
    const void* ln1_b    = d_in[9];
    const void* ff_w1    = d_in[10];
    const void* ff_b1    = d_in[11];
    const void* ff_w2    = d_in[12];
    const void* ff_b2    = d_in[13];
    const void* ln2_g    = d_in[14];
    const void* ln2_b    = d_in[15];

    int* flag = (int*)d_ws;
    float* ws = (float*)d_ws + 256;
    size_t off = 0;
    float* core = ws + off; off += (size_t)TGT_LEN * BSZ * D_MODEL;
    float* X    = ws + off; off += (size_t)TGT_LEN * BSZ * D_INNER;
    float* qb   = ws + off; off += (size_t)TGT_LEN * BSZ * D_MODEL;
    float* kb   = ws + off; off += (size_t)KLEN * BSZ * D_MODEL;
    float* vb   = ws + off; off += (size_t)KLEN * BSZ * D_MODEL;
    float* rkb  = ws + off; off += (size_t)KLEN * D_MODEL;
    float* posb = ws + off; off += (size_t)KLEN * D_MODEL;
    float* vecb = ws + off; off += (size_t)TGT_LEN * BSZ * D_MODEL;

    float* cat      = X;
    float* attn_out = X;
    float* h1       = X;
    float* ffb      = vecb;

    detect_kernel<<<1, 256, 0, stream>>>((const ushort*)emb, flag);
    embed_kernel<<<TGT_LEN * BSZ, 256, 0, stream>>>(inp, emb, core, flag);
    pos_kernel<<<KLEN, 256, 0, stream>>>(posb);

    for (int l = 0; l < N_LAYER; ++l) {
        const size_t qkv_off = (size_t)l * 3 * D_MODEL * D_MODEL;
        const size_t rw_off  = (size_t)l * D_MODEL * D_MODEL;
        const size_t ow_off  = (size_t)l * D_MODEL * D_MODEL;
        const size_t w1_off  = (size_t)l * D_INNER * D_MODEL;
        const size_t b1_off  = (size_t)l * D_INNER;
        const size_t w2_off  = (size_t)l * D_MODEL * D_INNER;
        const size_t b2_off  = (size_t)l * D_MODEL;
        const size_t mems_off = (size_t)l * MEM_LEN * BSZ * D_MODEL;
        const size_t ln_off  = (size_t)l * D_MODEL;

        concat_kernel<<<KLEN * BSZ, 256, 0, stream>>>(mems, mems_off, core, cat, flag);

        gemm_awt<false, false><<<dim3(D_MODEL / 64, (TGT_LEN * BSZ) / 64), 256, 0, stream>>>(
            cat + (size_t)MEM_LEN * BSZ * D_MODEL, qkv_w, qkv_off, nullptr, 0, qb,
            TGT_LEN * BSZ, D_MODEL, D_MODEL, flag);
        gemm_awt<false, false><<<dim3(D_MODEL / 64, (KLEN * BSZ) / 64), 256, 0, stream>>>(
            cat, qkv_w, qkv_off + (size_t)D_MODEL * D_MODEL, nullptr, 0, kb,
            KLEN * BSZ, D_MODEL, D_MODEL, flag);
        gemm_awt<false, false><<<dim3(D_MODEL / 64, (KLEN * BSZ) / 64), 256, 0, stream>>>(
            cat, qkv_w, qkv_off + (size_t)2 * D_MODEL * D_MODEL, nullptr, 0, vb,
            KLEN * BSZ, D_MODEL, D_MODEL, flag);
        gemm_awt<false, false><<<dim3(D_MODEL / 64, KLEN / 64), 256, 0, stream>>>(
            posb, r_w, rw_off, nullptr, 0, rkb, KLEN, D_MODEL, D_MODEL, flag);

        attn_flash_kernel<<<dim3(TGT_LEN / 64, BSZ, N_HEAD), 256, 0, stream>>>(
            qb, kb, vb, rkb, r_w_bias, r_r_bias, vecb, flag);

        gemm_awt<false, false><<<dim3(D_MODEL / 64, (TGT_LEN * BSZ) / 64), 256, 0, stream>>>(
            vecb, o_w, ow_off, nullptr, 0, attn_out, TGT_LEN * BSZ, D_MODEL, D_MODEL, flag);

        add_ln_kernel<<<TGT_LEN * BSZ, 256, 0, stream>>>(core, attn_out,
            ln1_g, ln_off, ln1_b, ln_off, flag);

        gemm_awt<true, true><<<dim3(D_INNER / 64, (TGT_LEN * BSZ) / 64), 256, 0, stream>>>(
            core, ff_w1, w1_off, ff_b1, b1_off, h1, TGT_LEN * BSZ, D_INNER, D_MODEL, flag);
        gemm_awt<true, false><<<dim3(D_MODEL / 64, (TGT_LEN * BSZ) / 64), 256, 0, stream>>>(
            h1, ff_w2, w2_off, ff_b2, b2_off, ffb, TGT_LEN * BSZ, D_MODEL, D_INNER, flag);

        add_ln_kernel<<<TGT_LEN * BSZ, 256, 0, stream>>>(core, ffb,
            ln2_g, ln_off, ln2_b, ln_off, flag);
    }

    cast_out_kernel<<<(TGT_LEN * BSZ * D_MODEL) / 256, 256, 0, stream>>>(
        core, d_out, flag);
}